// Round 15
// baseline (666.328 us; speedup 1.0000x reference)
//
#include <hip/hip_runtime.h>
#include <hip/hip_bf16.h>
#include <stdint.h>

#define N_NODES 50000
#define N_EDGES 800000
#define D 128
#define NPAD 50048
#define HKD 256   // bf16/fp8 row col count
#define KDIM 512

typedef __attribute__((ext_vector_type(8))) __bf16 bf16x8;
typedef __attribute__((ext_vector_type(4))) __bf16 bf16x4;
typedef __attribute__((ext_vector_type(4))) float f32x4;
typedef __attribute__((ext_vector_type(2))) float f32x2;

__device__ __forceinline__ void gload_lds16(const void* g, void* l) {
  __builtin_amdgcn_global_load_lds(
      (const __attribute__((address_space(1))) unsigned int*)(uintptr_t)g,
      (__attribute__((address_space(3))) unsigned int*)(uint32_t)(uintptr_t)l,
      16, 0, 0);
}

__device__ __forceinline__ float sigm(float v) { return 1.0f / (1.0f + __expf(-v)); }
__device__ __forceinline__ float tanh_fast(float v) { return 1.0f - 2.0f / (1.0f + __expf(2.0f * v)); }

// ---- fp8 e4m3 (OCP) pack/unpack via gfx950 HW converts (fallback: hip_fp8 API) ----
#if defined(__has_builtin) && __has_builtin(__builtin_amdgcn_cvt_pk_fp8_f32) && __has_builtin(__builtin_amdgcn_cvt_pk_f32_fp8)
__device__ __forceinline__ unsigned pack_fp8x4(float a, float b, float c, float d) {
  int p = __builtin_amdgcn_cvt_pk_fp8_f32(a, b, 0, false);
  p = __builtin_amdgcn_cvt_pk_fp8_f32(c, d, p, true);
  return (unsigned)p;
}
__device__ __forceinline__ f32x2 unpk_fp8_lo(unsigned u) { return __builtin_amdgcn_cvt_pk_f32_fp8(u, false); }
__device__ __forceinline__ f32x2 unpk_fp8_hi(unsigned u) { return __builtin_amdgcn_cvt_pk_f32_fp8(u, true); }
#else
#include <hip/hip_fp8.h>
__device__ __forceinline__ unsigned pack_fp8x4(float a, float b, float c, float d) {
  __hip_fp8_e4m3 qa(a), qb(b), qc(c), qd(d);
  return (unsigned)qa.__x | ((unsigned)qb.__x << 8) | ((unsigned)qc.__x << 16) | ((unsigned)qd.__x << 24);
}
__device__ __forceinline__ float unpk1(unsigned byte) {
  __hip_fp8_e4m3 t; t.__x = (__hip_fp8_storage_t)byte; return (float)t;
}
__device__ __forceinline__ f32x2 unpk_fp8_lo(unsigned u) { f32x2 r; r.x = unpk1(u & 0xff); r.y = unpk1((u >> 8) & 0xff); return r; }
__device__ __forceinline__ f32x2 unpk_fp8_hi(unsigned u) { f32x2 r; r.x = unpk1((u >> 16) & 0xff); r.y = unpk1(u >> 24); return r; }
#endif

// ---------------- merged prep: deg count + fp32 -> {bf16 XHb(=out_h), fp8 XH8} + W pack ------
#define NB_DEG 3125   // 800000/256
#define NB_TOB 6250   // 50000*32/256
#define NB_PKW 1024   // 262144/256
__global__ void k_pre(const int* __restrict__ dst, int* __restrict__ deg,
                      const float* __restrict__ x, const float* __restrict__ h,
                      __bf16* __restrict__ XHb, uint8_t* __restrict__ XH8,
                      const float* __restrict__ Wx_self, const float* __restrict__ Wx_neigh,
                      const float* __restrict__ Wh_self, const float* __restrict__ Wh_neigh,
                      __bf16* __restrict__ Wp) {
  int b = blockIdx.x;
  if (b < NB_DEG) {
    int e = b * 256 + threadIdx.x;
    atomicAdd(&deg[dst[e]], 1);  // grid exact: 3125*256 == 800000
  } else if (b < NB_DEG + NB_TOB) {
    int idx = (b - NB_DEG) * 256 + threadIdx.x;  // 1.6M threads, 4 feats each, exact
    int node = idx >> 5;
    int f4 = (idx & 31) << 2;
    float4 xv = *(const float4*)(x + (size_t)node * D + f4);
    float4 hv = *(const float4*)(h + (size_t)node * D + f4);
    bf16x4 a, bb;
    a[0] = (__bf16)xv.x; a[1] = (__bf16)xv.y; a[2] = (__bf16)xv.z; a[3] = (__bf16)xv.w;
    bb[0] = (__bf16)hv.x; bb[1] = (__bf16)hv.y; bb[2] = (__bf16)hv.z; bb[3] = (__bf16)hv.w;
    __bf16* br = XHb + (size_t)node * HKD;
    *(bf16x4*)(br + f4) = a;
    *(bf16x4*)(br + 128 + f4) = bb;
    uint8_t* r8 = XH8 + (size_t)node * HKD;
    *(unsigned*)(r8 + f4) = pack_fp8x4(xv.x, xv.y, xv.z, xv.w);
    *(unsigned*)(r8 + 128 + f4) = pack_fp8x4(hv.x, hv.y, hv.z, hv.w);
  } else {
    int idx = (b - NB_DEG - NB_TOB) * 256 + threadIdx.x;  // 0..262143
    int e = idx & 7;
    int r16 = (idx >> 3) & 15;
    int q = (idx >> 7) & 3;
    int s = (idx >> 9) & 15;
    int G = idx >> 13;           // 0..31
    int wrow = G * 16 + r16;     // gate*128 + o
    int g = wrow >> 7, o = wrow & 127;
    int k = s * 32 + q * 8 + e;
    const float* src; int i;
    if (k < 128)      { src = Wx_self;  i = k; }
    else if (k < 256) { src = Wh_self;  i = k - 128; }
    else if (k < 384) { src = Wx_neigh; i = k - 256; }
    else              { src = Wh_neigh; i = k - 384; }
    Wp[idx] = (__bf16)src[(g << 14) + (i << 7) + o];
  }
}

// ---------------- single-block exclusive scan (50000 ints, 1024 thr, 8 ints/thread) ---------
__global__ __launch_bounds__(1024) void k_scan(const int* __restrict__ deg, int* __restrict__ offs,
                                               int* __restrict__ cursor, int n) {
  const int t = threadIdx.x;
  const int lane = t & 63;
  const int w = t >> 6;  // 0..15
  __shared__ int wsum[16];
  __shared__ int carry_s;
  int carry = 0;
  for (int base = 0; base < n; base += 8192) {
    int idx = base + t * 8;
    int4 v0 = make_int4(0, 0, 0, 0), v1 = make_int4(0, 0, 0, 0);
    if (idx < n) {  // n % 8 == 0, no straddle
      v0 = *(const int4*)(deg + idx);
      v1 = *(const int4*)(deg + idx + 4);
    }
    int tsum = v0.x + v0.y + v0.z + v0.w + v1.x + v1.y + v1.z + v1.w;
    int s = tsum;
#pragma unroll
    for (int d = 1; d < 64; d <<= 1) {
      int u = __shfl_up(s, d, 64);
      if (lane >= d) s += u;
    }
    if (lane == 63) wsum[w] = s;
    __syncthreads();
    int woff = 0;
    for (int i = 0; i < w; i++) woff += wsum[i];
    int excl = carry + woff + (s - tsum);
    if (idx < n) {
      int4 o0, o1;
      o0.x = excl;        o0.y = o0.x + v0.x; o0.z = o0.y + v0.y; o0.w = o0.z + v0.z;
      o1.x = o0.w + v0.w; o1.y = o1.x + v1.x; o1.z = o1.y + v1.y; o1.w = o1.z + v1.z;
      *(int4*)(offs + idx) = o0;     *(int4*)(offs + idx + 4) = o1;
      *(int4*)(cursor + idx) = o0;   *(int4*)(cursor + idx + 4) = o1;
    }
    __syncthreads();
    if (t == 0) {
      int tot = carry;
#pragma unroll
      for (int i = 0; i < 16; i++) tot += wsum[i];
      carry_s = tot;
    }
    __syncthreads();
    carry = carry_s;
  }
  if (t == 0) offs[n] = carry;
}

// ---------------- fill CSR bins ----------------
__global__ void k_fill(const int* __restrict__ src, const int* __restrict__ dst,
                       int* __restrict__ cursor, int* __restrict__ bins) {
  int e = blockIdx.x * 256 + threadIdx.x;
  if (e < N_EDGES) {
    int d = dst[e];
    int p = atomicAdd(&cursor[d], 1);
    bins[p] = src[e];
  }
}

// ---------------- gather means from fp8 rows: 1 wave/node, 8 edges in flight ----------------
// reads XH8 rows (256 B), writes ZM(=out_c) row bf16: [ mean_x(0-127) | mean_h(128-255) ]
__global__ void k_gather(const int* __restrict__ offs, const int* __restrict__ bins,
                         const uint8_t* __restrict__ XH8, __bf16* __restrict__ ZM) {
  int wid = (blockIdx.x * 256 + threadIdx.x) >> 6;
  int lane = threadIdx.x & 63;
  if (wid >= N_NODES) return;
  const int half = lane >> 5;
  const int li = lane & 31;
  const int boff = li * 8;  // byte offset into the 256B row
  int beg = offs[wid], end = offs[wid + 1];
  float a[8] = {0.f, 0.f, 0.f, 0.f, 0.f, 0.f, 0.f, 0.f};
  auto acc = [&](uint2 v) {
    f32x2 p;
    p = unpk_fp8_lo(v.x); a[0] += p.x; a[1] += p.y;
    p = unpk_fp8_hi(v.x); a[2] += p.x; a[3] += p.y;
    p = unpk_fp8_lo(v.y); a[4] += p.x; a[5] += p.y;
    p = unpk_fp8_hi(v.y); a[6] += p.x; a[7] += p.y;
  };
  int j = beg + half;
  for (; j + 6 < end; j += 8) {  // 4 edges in flight per half-wave
    int s0 = bins[j], s1 = bins[j + 2], s2 = bins[j + 4], s3 = bins[j + 6];
    uint2 v0 = *(const uint2*)(XH8 + (size_t)s0 * HKD + boff);
    uint2 v1 = *(const uint2*)(XH8 + (size_t)s1 * HKD + boff);
    uint2 v2 = *(const uint2*)(XH8 + (size_t)s2 * HKD + boff);
    uint2 v3 = *(const uint2*)(XH8 + (size_t)s3 * HKD + boff);
    acc(v0); acc(v1); acc(v2); acc(v3);
  }
  for (; j < end; j += 2) {
    uint2 v = *(const uint2*)(XH8 + (size_t)bins[j] * HKD + boff);
    acc(v);
  }
#pragma unroll
  for (int e = 0; e < 8; ++e) a[e] += __shfl_xor(a[e], 32, 64);
  int degn = end - beg;
  float inv = 1.0f / (float)(degn > 0 ? degn : 1);
  if (lane < 32) {
    bf16x8 bb;
#pragma unroll
    for (int e = 0; e < 8; ++e) bb[e] = (__bf16)(a[e] * inv);
    *(bf16x8*)(ZM + (size_t)wid * HKD + boff) = bb;
  }
}

// ---------------- fused GEMM + LSTM epilogue: BM=128, LDS time-shared between K-halves -------
// 512 thr / 8 waves, BM=128, BN=512. B-traffic per block (512 KB) now amortized over 128 rows
// (total B bytes halve chip-wide: the measured L2-BW bottleneck). 64 KB LDS holds ONE K-half
// of the A-tile (128 rows x 256 k); the two halves time-share it:
//   stage self -> vmcnt(0)+bar -> steps 0-7 -> lgkmcnt(0)+bar (phase-1 ds_reads are in regs
//   before any wave passes) -> stage means into SAME slots -> vmcnt(0)+bar -> steps 8-15.
// 2 blocks/CU (grid 391 <= 512 resident slots: single dispatch round). acc[8][4]=128 AGPR.
__global__ __launch_bounds__(512, 4) void k_gemm(
    const __bf16* __restrict__ XHb, const __bf16* __restrict__ ZM, const __bf16* __restrict__ Wp,
    const float* __restrict__ c,
    const float* __restrict__ w_ci, const float* __restrict__ w_cf, const float* __restrict__ w_co,
    const float* __restrict__ b_i, const float* __restrict__ b_f, const float* __restrict__ b_c,
    const float* __restrict__ b_o,
    float* __restrict__ out_h, float* __restrict__ out_c) {
  __shared__ __align__(16) __bf16 As[4096 * 8];  // 64 KB; slot = row*32 + chunk (128 rows)
  const int t = threadIdx.x;
  const int lane = t & 63;
  const int w = t >> 6;  // 0..7
  const int m0 = blockIdx.x * 128;
  const int l15 = lane & 15;
  const int q = lane >> 4;  // 0..3

  // ---- stage SELF half (k 0-255) for all 128 rows: linear dest, source chunk swizzled ----
#pragma unroll
  for (int i = 0; i < 8; ++i) {
    int u = i * 512 + t;           // 0..4095
    int row = u >> 5, cz = u & 31;
    int cg = cz ^ (row & 7);
    int grow = m0 + row;
    if (grow >= N_NODES) grow = N_NODES - 1;  // pad rows: stage real data, discard later
    gload_lds16(XHb + (size_t)grow * HKD + cg * 8, (__bf16*)As + (size_t)u * 8);
  }

  f32x4 acc[8][4];
#pragma unroll
  for (int m = 0; m < 8; ++m)
#pragma unroll
    for (int g = 0; g < 4; ++g) acc[m][g] = (f32x4){0.f, 0.f, 0.f, 0.f};

  auto LOADA = [&](int sl, bf16x8* af) {  // sl = step within current half (0..7)
    const int cq = sl * 4 + q;
#pragma unroll
    for (int m = 0; m < 8; ++m) {
      int row = m * 16 + l15;
      af[m] = *(const bf16x8*)((__bf16*)As + (size_t)(row * 32 + (cq ^ (row & 7))) * 8);
    }
  };

  // B frag base: frag g, step s -> Wp + ((g*8 + w)*16 + s)*512 + lane*8
  const __bf16* wp = Wp + (size_t)(w * 16) * 512 + lane * 8;
  bf16x8 bA[4], bB[4];
#pragma unroll
  for (int g = 0; g < 4; ++g) bA[g] = *(const bf16x8*)(wp + g * 65536);

  // ---- phase 1: self half landed ----
  asm volatile("s_waitcnt vmcnt(0)" ::: "memory");
  __builtin_amdgcn_s_barrier();
  __builtin_amdgcn_sched_barrier(0);
#pragma unroll
  for (int s2 = 0; s2 < 4; ++s2) {
    {  // even step: compute bA, prefetch bB
      const int step = 2 * s2;
#pragma unroll
      for (int g = 0; g < 4; ++g)
        bB[g] = *(const bf16x8*)(wp + g * 65536 + (step + 1) * 512);
      bf16x8 af[8];
      LOADA(step, af);
      __builtin_amdgcn_s_setprio(1);
#pragma unroll
      for (int m = 0; m < 8; ++m)
#pragma unroll
        for (int g = 0; g < 4; ++g)
          acc[m][g] = __builtin_amdgcn_mfma_f32_16x16x32_bf16(af[m], bA[g], acc[m][g], 0, 0, 0);
      __builtin_amdgcn_s_setprio(0);
    }
    {  // odd step: compute bB, prefetch bA
      const int step = 2 * s2 + 1;
#pragma unroll
      for (int g = 0; g < 4; ++g)
        bA[g] = *(const bf16x8*)(wp + g * 65536 + (step + 1) * 512);
      bf16x8 af[8];
      LOADA(step, af);
      __builtin_amdgcn_s_setprio(1);
#pragma unroll
      for (int m = 0; m < 8; ++m)
#pragma unroll
        for (int g = 0; g < 4; ++g)
          acc[m][g] = __builtin_amdgcn_mfma_f32_16x16x32_bf16(af[m], bB[g], acc[m][g], 0, 0, 0);
      __builtin_amdgcn_s_setprio(0);
    }
  }

  // ---- all phase-1 LDS reads are in registers; reuse LDS for the MEAN half ----
  asm volatile("s_waitcnt lgkmcnt(0)" ::: "memory");
  __builtin_amdgcn_s_barrier();
  __builtin_amdgcn_sched_barrier(0);
#pragma unroll
  for (int i = 0; i < 8; ++i) {
    int u = i * 512 + t;
    int row = u >> 5, cz = u & 31;
    int cg = cz ^ (row & 7);
    int grow = m0 + row;
    if (grow >= N_NODES) grow = N_NODES - 1;
    gload_lds16(ZM + (size_t)grow * HKD + cg * 8, (__bf16*)As + (size_t)u * 8);
  }
  asm volatile("s_waitcnt vmcnt(0)" ::: "memory");
  __builtin_amdgcn_s_barrier();
  __builtin_amdgcn_sched_barrier(0);

  // ---- phase 2: mean half (global steps 8..15; bA for step 8 prefetched at step 7) ----
#pragma unroll
  for (int s2 = 4; s2 < 8; ++s2) {
    {  // even step: compute bA, prefetch bB
      const int step = 2 * s2;
#pragma unroll
      for (int g = 0; g < 4; ++g)
        bB[g] = *(const bf16x8*)(wp + g * 65536 + (step + 1) * 512);
      bf16x8 af[8];
      LOADA(step - 8, af);
      __builtin_amdgcn_s_setprio(1);
#pragma unroll
      for (int m = 0; m < 8; ++m)
#pragma unroll
        for (int g = 0; g < 4; ++g)
          acc[m][g] = __builtin_amdgcn_mfma_f32_16x16x32_bf16(af[m], bA[g], acc[m][g], 0, 0, 0);
      __builtin_amdgcn_s_setprio(0);
    }
    {  // odd step: compute bB, prefetch bA
      const int step = 2 * s2 + 1;
      if (step < 15) {
#pragma unroll
        for (int g = 0; g < 4; ++g)
          bA[g] = *(const bf16x8*)(wp + g * 65536 + (step + 1) * 512);
      }
      bf16x8 af[8];
      LOADA(step - 8, af);
      __builtin_amdgcn_s_setprio(1);
#pragma unroll
      for (int m = 0; m < 8; ++m)
#pragma unroll
        for (int g = 0; g < 4; ++g)
          acc[m][g] = __builtin_amdgcn_mfma_f32_16x16x32_bf16(af[m], bB[g], acc[m][g], 0, 0, 0);
      __builtin_amdgcn_s_setprio(0);
    }
  }

  // epilogue: LSTM cell math, fused (rows m0..m0+127 owned exclusively by this block)
  const int o = w * 16 + l15;
  const float wci = w_ci[o], wcf = w_cf[o], wco = w_co[o];
  const float bi = b_i[o], bfv = b_f[o], bc = b_c[o], bo = b_o[o];
#pragma unroll
  for (int m = 0; m < 8; ++m) {
#pragma unroll
    for (int r = 0; r < 4; ++r) {
      int row = m0 + m * 16 + q * 4 + r;
      if (row < N_NODES) {
        float cv = c[(size_t)row * D + o];
        float ig = sigm(acc[m][0][r] + wci * cv + bi);
        float fg = sigm(acc[m][1][r] + wcf * cv + bfv);
        float ct = tanh_fast(acc[m][2][r] + bc);
        float nc = fg * cv + ig * ct;
        float og = sigm(acc[m][3][r] + wco * nc + bo);
        out_h[(size_t)row * D + o] = og * tanh_fast(nc);
        out_c[(size_t)row * D + o] = nc;
      }
    }
  }
}

extern "C" void kernel_launch(void* const* d_in, const int* in_sizes, int n_in,
                              void* d_out, int out_size, void* d_ws, size_t ws_size,
                              hipStream_t stream) {
  const float* x = (const float*)d_in[0];
  const float* h = (const float*)d_in[1];
  const float* c = (const float*)d_in[2];
  const float* Wx_self = (const float*)d_in[3];
  const float* Wx_neigh = (const float*)d_in[4];
  const float* Wh_self = (const float*)d_in[5];
  const float* Wh_neigh = (const float*)d_in[6];
  const float* w_ci = (const float*)d_in[7];
  const float* w_cf = (const float*)d_in[8];
  const float* w_co = (const float*)d_in[9];
  const float* b_i = (const float*)d_in[10];
  const float* b_f = (const float*)d_in[11];
  const float* b_c = (const float*)d_in[12];
  const float* b_o = (const float*)d_in[13];
  const int* src = (const int*)d_in[14];
  const int* dst = (const int*)d_in[15];

  char* ws = (char*)d_ws;
  int* deg = (int*)(ws);                       // 50000 ints
  int* offs = (int*)(ws + 200704);             // 50001 ints
  int* cursor = (int*)(ws + 400896);           // 50000 ints
  int* bins = (int*)(ws + 601088);             // 800000 ints (ends 3,801,088)
  uint8_t* XH8 = (uint8_t*)(ws + 4194304);     // [50000][256] fp8 = 12.8 MB
  __bf16* Wp = (__bf16*)(ws + 17039360);       // [262144] bf16 frag-major

  float* out_h = (float*)d_out;
  float* out_c = out_h + (size_t)N_NODES * D;
  // staging aliases inside d_out (block-local rows; overwritten by epilogue after reads)
  __bf16* XHb = (__bf16*)out_h;  // [50000][256] bf16 self rows
  __bf16* ZM = (__bf16*)out_c;   // [50000][256] bf16 mean rows

  hipMemsetAsync(deg, 0, N_NODES * sizeof(int), stream);
  k_pre<<<NB_DEG + NB_TOB + NB_PKW, 256, 0, stream>>>(dst, deg, x, h, XHb, XH8,
                                                      Wx_self, Wx_neigh, Wh_self, Wh_neigh, Wp);
  k_scan<<<1, 1024, 0, stream>>>(deg, offs, cursor, N_NODES);
  k_fill<<<(N_EDGES + 255) / 256, 256, 0, stream>>>(src, dst, cursor, bins);
  k_gather<<<(N_NODES + 3) / 4, 256, 0, stream>>>(offs, bins, XH8, ZM);
  k_gemm<<<NPAD / 128, 512, 0, stream>>>(XHb, ZM, Wp, c, w_ci, w_cf, w_co,
                                         b_i, b_f, b_c, b_o, out_h, out_c);
}

// Round 16
// 234.646 us; speedup vs baseline: 2.8397x; 2.8397x over previous
//
#include <hip/hip_runtime.h>
#include <hip/hip_bf16.h>
#include <stdint.h>

#define N_NODES 50000
#define N_EDGES 800000
#define D 128
#define NPAD 50048
#define HKD 256   // bf16/fp8 row col count
#define KDIM 512

typedef __attribute__((ext_vector_type(8))) __bf16 bf16x8;
typedef __attribute__((ext_vector_type(4))) __bf16 bf16x4;
typedef __attribute__((ext_vector_type(4))) float f32x4;
typedef __attribute__((ext_vector_type(2))) float f32x2;

__device__ __forceinline__ void gload_lds16(const void* g, void* l) {
  __builtin_amdgcn_global_load_lds(
      (const __attribute__((address_space(1))) unsigned int*)(uintptr_t)g,
      (__attribute__((address_space(3))) unsigned int*)(uint32_t)(uintptr_t)l,
      16, 0, 0);
}

__device__ __forceinline__ float sigm(float v) { return 1.0f / (1.0f + __expf(-v)); }
__device__ __forceinline__ float tanh_fast(float v) { return 1.0f - 2.0f / (1.0f + __expf(2.0f * v)); }

// ---- fp8 e4m3 (OCP) pack/unpack via gfx950 HW converts (fallback: hip_fp8 API) ----
#if defined(__has_builtin) && __has_builtin(__builtin_amdgcn_cvt_pk_fp8_f32) && __has_builtin(__builtin_amdgcn_cvt_pk_f32_fp8)
__device__ __forceinline__ unsigned pack_fp8x4(float a, float b, float c, float d) {
  int p = __builtin_amdgcn_cvt_pk_fp8_f32(a, b, 0, false);
  p = __builtin_amdgcn_cvt_pk_fp8_f32(c, d, p, true);
  return (unsigned)p;
}
__device__ __forceinline__ f32x2 unpk_fp8_lo(unsigned u) { return __builtin_amdgcn_cvt_pk_f32_fp8(u, false); }
__device__ __forceinline__ f32x2 unpk_fp8_hi(unsigned u) { return __builtin_amdgcn_cvt_pk_f32_fp8(u, true); }
#else
#include <hip/hip_fp8.h>
__device__ __forceinline__ unsigned pack_fp8x4(float a, float b, float c, float d) {
  __hip_fp8_e4m3 qa(a), qb(b), qc(c), qd(d);
  return (unsigned)qa.__x | ((unsigned)qb.__x << 8) | ((unsigned)qc.__x << 16) | ((unsigned)qd.__x << 24);
}
__device__ __forceinline__ float unpk1(unsigned byte) {
  __hip_fp8_e4m3 t; t.__x = (__hip_fp8_storage_t)byte; return (float)t;
}
__device__ __forceinline__ f32x2 unpk_fp8_lo(unsigned u) { f32x2 r; r.x = unpk1(u & 0xff); r.y = unpk1((u >> 8) & 0xff); return r; }
__device__ __forceinline__ f32x2 unpk_fp8_hi(unsigned u) { f32x2 r; r.x = unpk1((u >> 16) & 0xff); r.y = unpk1(u >> 24); return r; }
#endif

// ---------------- merged prep: deg count + fp32 -> {bf16 XHb(=out_h), fp8 XH8} + W pack ------
#define NB_DEG 3125   // 800000/256
#define NB_TOB 6250   // 50000*32/256
#define NB_PKW 1024   // 262144/256
__global__ void k_pre(const int* __restrict__ dst, int* __restrict__ deg,
                      const float* __restrict__ x, const float* __restrict__ h,
                      __bf16* __restrict__ XHb, uint8_t* __restrict__ XH8,
                      const float* __restrict__ Wx_self, const float* __restrict__ Wx_neigh,
                      const float* __restrict__ Wh_self, const float* __restrict__ Wh_neigh,
                      __bf16* __restrict__ Wp) {
  int b = blockIdx.x;
  if (b < NB_DEG) {
    int e = b * 256 + threadIdx.x;
    atomicAdd(&deg[dst[e]], 1);  // grid exact: 3125*256 == 800000
  } else if (b < NB_DEG + NB_TOB) {
    int idx = (b - NB_DEG) * 256 + threadIdx.x;  // 1.6M threads, 4 feats each, exact
    int node = idx >> 5;
    int f4 = (idx & 31) << 2;
    float4 xv = *(const float4*)(x + (size_t)node * D + f4);
    float4 hv = *(const float4*)(h + (size_t)node * D + f4);
    bf16x4 a, bb;
    a[0] = (__bf16)xv.x; a[1] = (__bf16)xv.y; a[2] = (__bf16)xv.z; a[3] = (__bf16)xv.w;
    bb[0] = (__bf16)hv.x; bb[1] = (__bf16)hv.y; bb[2] = (__bf16)hv.z; bb[3] = (__bf16)hv.w;
    __bf16* br = XHb + (size_t)node * HKD;
    *(bf16x4*)(br + f4) = a;
    *(bf16x4*)(br + 128 + f4) = bb;
    uint8_t* r8 = XH8 + (size_t)node * HKD;
    *(unsigned*)(r8 + f4) = pack_fp8x4(xv.x, xv.y, xv.z, xv.w);
    *(unsigned*)(r8 + 128 + f4) = pack_fp8x4(hv.x, hv.y, hv.z, hv.w);
  } else {
    int idx = (b - NB_DEG - NB_TOB) * 256 + threadIdx.x;  // 0..262143
    int e = idx & 7;
    int r16 = (idx >> 3) & 15;
    int q = (idx >> 7) & 3;
    int s = (idx >> 9) & 15;
    int G = idx >> 13;           // 0..31
    int wrow = G * 16 + r16;     // gate*128 + o
    int g = wrow >> 7, o = wrow & 127;
    int k = s * 32 + q * 8 + e;
    const float* src; int i;
    if (k < 128)      { src = Wx_self;  i = k; }
    else if (k < 256) { src = Wh_self;  i = k - 128; }
    else if (k < 384) { src = Wx_neigh; i = k - 256; }
    else              { src = Wh_neigh; i = k - 384; }
    Wp[idx] = (__bf16)src[(g << 14) + (i << 7) + o];
  }
}

// ---------------- single-block exclusive scan (50000 ints, 1024 thr, 8 ints/thread) ---------
__global__ __launch_bounds__(1024) void k_scan(const int* __restrict__ deg, int* __restrict__ offs,
                                               int* __restrict__ cursor, int n) {
  const int t = threadIdx.x;
  const int lane = t & 63;
  const int w = t >> 6;  // 0..15
  __shared__ int wsum[16];
  __shared__ int carry_s;
  int carry = 0;
  for (int base = 0; base < n; base += 8192) {
    int idx = base + t * 8;
    int4 v0 = make_int4(0, 0, 0, 0), v1 = make_int4(0, 0, 0, 0);
    if (idx < n) {  // n % 8 == 0, no straddle
      v0 = *(const int4*)(deg + idx);
      v1 = *(const int4*)(deg + idx + 4);
    }
    int tsum = v0.x + v0.y + v0.z + v0.w + v1.x + v1.y + v1.z + v1.w;
    int s = tsum;
#pragma unroll
    for (int d = 1; d < 64; d <<= 1) {
      int u = __shfl_up(s, d, 64);
      if (lane >= d) s += u;
    }
    if (lane == 63) wsum[w] = s;
    __syncthreads();
    int woff = 0;
    for (int i = 0; i < w; i++) woff += wsum[i];
    int excl = carry + woff + (s - tsum);
    if (idx < n) {
      int4 o0, o1;
      o0.x = excl;        o0.y = o0.x + v0.x; o0.z = o0.y + v0.y; o0.w = o0.z + v0.z;
      o1.x = o0.w + v0.w; o1.y = o1.x + v1.x; o1.z = o1.y + v1.y; o1.w = o1.z + v1.z;
      *(int4*)(offs + idx) = o0;     *(int4*)(offs + idx + 4) = o1;
      *(int4*)(cursor + idx) = o0;   *(int4*)(cursor + idx + 4) = o1;
    }
    __syncthreads();
    if (t == 0) {
      int tot = carry;
#pragma unroll
      for (int i = 0; i < 16; i++) tot += wsum[i];
      carry_s = tot;
    }
    __syncthreads();
    carry = carry_s;
  }
  if (t == 0) offs[n] = carry;
}

// ---------------- fill CSR bins ----------------
__global__ void k_fill(const int* __restrict__ src, const int* __restrict__ dst,
                       int* __restrict__ cursor, int* __restrict__ bins) {
  int e = blockIdx.x * 256 + threadIdx.x;
  if (e < N_EDGES) {
    int d = dst[e];
    int p = atomicAdd(&cursor[d], 1);
    bins[p] = src[e];
  }
}

// ---------------- gather means from fp8 rows: 1 wave/node, 8 edges in flight ----------------
// reads XH8 rows (256 B), writes ZM(=out_c) row bf16: [ mean_x(0-127) | mean_h(128-255) ]
__global__ void k_gather(const int* __restrict__ offs, const int* __restrict__ bins,
                         const uint8_t* __restrict__ XH8, __bf16* __restrict__ ZM) {
  int wid = (blockIdx.x * 256 + threadIdx.x) >> 6;
  int lane = threadIdx.x & 63;
  if (wid >= N_NODES) return;
  const int half = lane >> 5;
  const int li = lane & 31;
  const int boff = li * 8;  // byte offset into the 256B row
  int beg = offs[wid], end = offs[wid + 1];
  float a[8] = {0.f, 0.f, 0.f, 0.f, 0.f, 0.f, 0.f, 0.f};
  auto acc = [&](uint2 v) {
    f32x2 p;
    p = unpk_fp8_lo(v.x); a[0] += p.x; a[1] += p.y;
    p = unpk_fp8_hi(v.x); a[2] += p.x; a[3] += p.y;
    p = unpk_fp8_lo(v.y); a[4] += p.x; a[5] += p.y;
    p = unpk_fp8_hi(v.y); a[6] += p.x; a[7] += p.y;
  };
  int j = beg + half;
  for (; j + 6 < end; j += 8) {  // 4 edges in flight per half-wave
    int s0 = bins[j], s1 = bins[j + 2], s2 = bins[j + 4], s3 = bins[j + 6];
    uint2 v0 = *(const uint2*)(XH8 + (size_t)s0 * HKD + boff);
    uint2 v1 = *(const uint2*)(XH8 + (size_t)s1 * HKD + boff);
    uint2 v2 = *(const uint2*)(XH8 + (size_t)s2 * HKD + boff);
    uint2 v3 = *(const uint2*)(XH8 + (size_t)s3 * HKD + boff);
    acc(v0); acc(v1); acc(v2); acc(v3);
  }
  for (; j < end; j += 2) {
    uint2 v = *(const uint2*)(XH8 + (size_t)bins[j] * HKD + boff);
    acc(v);
  }
#pragma unroll
  for (int e = 0; e < 8; ++e) a[e] += __shfl_xor(a[e], 32, 64);
  int degn = end - beg;
  float inv = 1.0f / (float)(degn > 0 ? degn : 1);
  if (lane < 32) {
    bf16x8 bb;
#pragma unroll
    for (int e = 0; e < 8; ++e) bb[e] = (__bf16)(a[e] * inv);
    *(bf16x8*)(ZM + (size_t)wid * HKD + boff) = bb;
  }
}

// ---------------- fused GEMM + LSTM epilogue: BM=128, LDS time-shared between K-halves -------
// 512 thr / 8 waves, BM=128, BN=512, __launch_bounds__(512,2): 256-reg budget so
// acc[8][4]=128 AGPR stays in registers (R15's (512,4) spilled to scratch: 1.2GB writes).
// 1 block/CU; B-traffic per K-step per CU halves vs BM=64 (the L2-BW bottleneck).
// 64 KB LDS holds ONE K-half (128 rows x 256 k); halves time-share it:
//   stage self -> vmcnt(0)+bar -> steps 0-7 -> lgkmcnt(0)+bar -> stage means (same slots)
//   -> vmcnt(0)+bar -> steps 8-15 -> LSTM epilogue.
__global__ __launch_bounds__(512, 2) void k_gemm(
    const __bf16* __restrict__ XHb, const __bf16* __restrict__ ZM, const __bf16* __restrict__ Wp,
    const float* __restrict__ c,
    const float* __restrict__ w_ci, const float* __restrict__ w_cf, const float* __restrict__ w_co,
    const float* __restrict__ b_i, const float* __restrict__ b_f, const float* __restrict__ b_c,
    const float* __restrict__ b_o,
    float* __restrict__ out_h, float* __restrict__ out_c) {
  __shared__ __align__(16) __bf16 As[4096 * 8];  // 64 KB; slot = row*32 + chunk (128 rows)
  const int t = threadIdx.x;
  const int lane = t & 63;
  const int w = t >> 6;  // 0..7
  const int m0 = blockIdx.x * 128;
  const int l15 = lane & 15;
  const int q = lane >> 4;  // 0..3

  // ---- stage SELF half (k 0-255) for all 128 rows: linear dest, source chunk swizzled ----
#pragma unroll
  for (int i = 0; i < 8; ++i) {
    int u = i * 512 + t;           // 0..4095
    int row = u >> 5, cz = u & 31;
    int cg = cz ^ (row & 7);
    int grow = m0 + row;
    if (grow >= N_NODES) grow = N_NODES - 1;  // pad rows: stage real data, discard later
    gload_lds16(XHb + (size_t)grow * HKD + cg * 8, (__bf16*)As + (size_t)u * 8);
  }

  f32x4 acc[8][4];
#pragma unroll
  for (int m = 0; m < 8; ++m)
#pragma unroll
    for (int g = 0; g < 4; ++g) acc[m][g] = (f32x4){0.f, 0.f, 0.f, 0.f};

  auto LOADA = [&](int sl, bf16x8* af) {  // sl = step within current half (0..7)
    const int cq = sl * 4 + q;
#pragma unroll
    for (int m = 0; m < 8; ++m) {
      int row = m * 16 + l15;
      af[m] = *(const bf16x8*)((__bf16*)As + (size_t)(row * 32 + (cq ^ (row & 7))) * 8);
    }
  };

  // B frag base: frag g, step s -> Wp + ((g*8 + w)*16 + s)*512 + lane*8
  const __bf16* wp = Wp + (size_t)(w * 16) * 512 + lane * 8;
  bf16x8 bA[4], bB[4];
#pragma unroll
  for (int g = 0; g < 4; ++g) bA[g] = *(const bf16x8*)(wp + g * 65536);

  // ---- phase 1: self half landed ----
  asm volatile("s_waitcnt vmcnt(0)" ::: "memory");
  __builtin_amdgcn_s_barrier();
  __builtin_amdgcn_sched_barrier(0);
#pragma unroll
  for (int s2 = 0; s2 < 4; ++s2) {
    {  // even step: compute bA, prefetch bB
      const int step = 2 * s2;
#pragma unroll
      for (int g = 0; g < 4; ++g)
        bB[g] = *(const bf16x8*)(wp + g * 65536 + (step + 1) * 512);
      bf16x8 af[8];
      LOADA(step, af);
      __builtin_amdgcn_s_setprio(1);
#pragma unroll
      for (int m = 0; m < 8; ++m)
#pragma unroll
        for (int g = 0; g < 4; ++g)
          acc[m][g] = __builtin_amdgcn_mfma_f32_16x16x32_bf16(af[m], bA[g], acc[m][g], 0, 0, 0);
      __builtin_amdgcn_s_setprio(0);
    }
    {  // odd step: compute bB, prefetch bA
      const int step = 2 * s2 + 1;
#pragma unroll
      for (int g = 0; g < 4; ++g)
        bA[g] = *(const bf16x8*)(wp + g * 65536 + (step + 1) * 512);
      bf16x8 af[8];
      LOADA(step, af);
      __builtin_amdgcn_s_setprio(1);
#pragma unroll
      for (int m = 0; m < 8; ++m)
#pragma unroll
        for (int g = 0; g < 4; ++g)
          acc[m][g] = __builtin_amdgcn_mfma_f32_16x16x32_bf16(af[m], bB[g], acc[m][g], 0, 0, 0);
      __builtin_amdgcn_s_setprio(0);
    }
  }

  // ---- all phase-1 LDS reads are in registers; reuse LDS for the MEAN half ----
  asm volatile("s_waitcnt lgkmcnt(0)" ::: "memory");
  __builtin_amdgcn_s_barrier();
  __builtin_amdgcn_sched_barrier(0);
#pragma unroll
  for (int i = 0; i < 8; ++i) {
    int u = i * 512 + t;
    int row = u >> 5, cz = u & 31;
    int cg = cz ^ (row & 7);
    int grow = m0 + row;
    if (grow >= N_NODES) grow = N_NODES - 1;
    gload_lds16(ZM + (size_t)grow * HKD + cg * 8, (__bf16*)As + (size_t)u * 8);
  }
  asm volatile("s_waitcnt vmcnt(0)" ::: "memory");
  __builtin_amdgcn_s_barrier();
  __builtin_amdgcn_sched_barrier(0);

  // ---- phase 2: mean half (global steps 8..15; bA for step 8 prefetched at step 7) ----
#pragma unroll
  for (int s2 = 4; s2 < 8; ++s2) {
    {  // even step: compute bA, prefetch bB
      const int step = 2 * s2;
#pragma unroll
      for (int g = 0; g < 4; ++g)
        bB[g] = *(const bf16x8*)(wp + g * 65536 + (step + 1) * 512);
      bf16x8 af[8];
      LOADA(step - 8, af);
      __builtin_amdgcn_s_setprio(1);
#pragma unroll
      for (int m = 0; m < 8; ++m)
#pragma unroll
        for (int g = 0; g < 4; ++g)
          acc[m][g] = __builtin_amdgcn_mfma_f32_16x16x32_bf16(af[m], bA[g], acc[m][g], 0, 0, 0);
      __builtin_amdgcn_s_setprio(0);
    }
    {  // odd step: compute bB, prefetch bA
      const int step = 2 * s2 + 1;
      if (step < 15) {
#pragma unroll
        for (int g = 0; g < 4; ++g)
          bA[g] = *(const bf16x8*)(wp + g * 65536 + (step + 1) * 512);
      }
      bf16x8 af[8];
      LOADA(step - 8, af);
      __builtin_amdgcn_s_setprio(1);
#pragma unroll
      for (int m = 0; m < 8; ++m)
#pragma unroll
        for (int g = 0; g < 4; ++g)
          acc[m][g] = __builtin_amdgcn_mfma_f32_16x16x32_bf16(af[m], bB[g], acc[m][g], 0, 0, 0);
      __builtin_amdgcn_s_setprio(0);
    }
  }

  // epilogue: LSTM cell math, fused (rows m0..m0+127 owned exclusively by this block)
  const int o = w * 16 + l15;
  const float wci = w_ci[o], wcf = w_cf[o], wco = w_co[o];
  const float bi = b_i[o], bfv = b_f[o], bc = b_c[o], bo = b_o[o];
#pragma unroll
  for (int m = 0; m < 8; ++m) {
#pragma unroll
    for (int r = 0; r < 4; ++r) {
      int row = m0 + m * 16 + q * 4 + r;
      if (row < N_NODES) {
        float cv = c[(size_t)row * D + o];
        float ig = sigm(acc[m][0][r] + wci * cv + bi);
        float fg = sigm(acc[m][1][r] + wcf * cv + bfv);
        float ct = tanh_fast(acc[m][2][r] + bc);
        float nc = fg * cv + ig * ct;
        float og = sigm(acc[m][3][r] + wco * nc + bo);
        out_h[(size_t)row * D + o] = og * tanh_fast(nc);
        out_c[(size_t)row * D + o] = nc;
      }
    }
  }
}

extern "C" void kernel_launch(void* const* d_in, const int* in_sizes, int n_in,
                              void* d_out, int out_size, void* d_ws, size_t ws_size,
                              hipStream_t stream) {
  const float* x = (const float*)d_in[0];
  const float* h = (const float*)d_in[1];
  const float* c = (const float*)d_in[2];
  const float* Wx_self = (const float*)d_in[3];
  const float* Wx_neigh = (const float*)d_in[4];
  const float* Wh_self = (const float*)d_in[5];
  const float* Wh_neigh = (const float*)d_in[6];
  const float* w_ci = (const float*)d_in[7];
  const float* w_cf = (const float*)d_in[8];
  const float* w_co = (const float*)d_in[9];
  const float* b_i = (const float*)d_in[10];
  const float* b_f = (const float*)d_in[11];
  const float* b_c = (const float*)d_in[12];
  const float* b_o = (const float*)d_in[13];
  const int* src = (const int*)d_in[14];
  const int* dst = (const int*)d_in[15];

  char* ws = (char*)d_ws;
  int* deg = (int*)(ws);                       // 50000 ints
  int* offs = (int*)(ws + 200704);             // 50001 ints
  int* cursor = (int*)(ws + 400896);           // 50000 ints
  int* bins = (int*)(ws + 601088);             // 800000 ints (ends 3,801,088)
  uint8_t* XH8 = (uint8_t*)(ws + 4194304);     // [50000][256] fp8 = 12.8 MB
  __bf16* Wp = (__bf16*)(ws + 17039360);       // [262144] bf16 frag-major

  float* out_h = (float*)d_out;
  float* out_c = out_h + (size_t)N_NODES * D;
  // staging aliases inside d_out (block-local rows; overwritten by epilogue after reads)
  __bf16* XHb = (__bf16*)out_h;  // [50000][256] bf16 self rows
  __bf16* ZM = (__bf16*)out_c;   // [50000][256] bf16 mean rows

  hipMemsetAsync(deg, 0, N_NODES * sizeof(int), stream);
  k_pre<<<NB_DEG + NB_TOB + NB_PKW, 256, 0, stream>>>(dst, deg, x, h, XHb, XH8,
                                                      Wx_self, Wx_neigh, Wh_self, Wh_neigh, Wp);
  k_scan<<<1, 1024, 0, stream>>>(deg, offs, cursor, N_NODES);
  k_fill<<<(N_EDGES + 255) / 256, 256, 0, stream>>>(src, dst, cursor, bins);
  k_gather<<<(N_NODES + 3) / 4, 256, 0, stream>>>(offs, bins, XH8, ZM);
  k_gemm<<<NPAD / 128, 512, 0, stream>>>(XHb, ZM, Wp, c, w_ci, w_cf, w_co,
                                         b_i, b_f, b_c, b_o, out_h, out_c);
}

// Round 17
// 205.121 us; speedup vs baseline: 3.2485x; 1.1439x over previous
//
#include <hip/hip_runtime.h>
#include <hip/hip_bf16.h>
#include <stdint.h>

#define N_NODES 50000
#define N_EDGES 800000
#define D 128
#define NPAD 50048
#define HKD 256   // bf16/fp8 row col count
#define KDIM 512

typedef __attribute__((ext_vector_type(8))) __bf16 bf16x8;
typedef __attribute__((ext_vector_type(4))) __bf16 bf16x4;
typedef __attribute__((ext_vector_type(4))) float f32x4;
typedef __attribute__((ext_vector_type(2))) float f32x2;

__device__ __forceinline__ void gload_lds16(const void* g, void* l) {
  __builtin_amdgcn_global_load_lds(
      (const __attribute__((address_space(1))) unsigned int*)(uintptr_t)g,
      (__attribute__((address_space(3))) unsigned int*)(uint32_t)(uintptr_t)l,
      16, 0, 0);
}

__device__ __forceinline__ float sigm(float v) { return 1.0f / (1.0f + __expf(-v)); }
__device__ __forceinline__ float tanh_fast(float v) { return 1.0f - 2.0f / (1.0f + __expf(2.0f * v)); }

// ---- fp8 e4m3 (OCP) pack/unpack via gfx950 HW converts (fallback: hip_fp8 API) ----
#if defined(__has_builtin) && __has_builtin(__builtin_amdgcn_cvt_pk_fp8_f32) && __has_builtin(__builtin_amdgcn_cvt_pk_f32_fp8)
__device__ __forceinline__ unsigned pack_fp8x4(float a, float b, float c, float d) {
  int p = __builtin_amdgcn_cvt_pk_fp8_f32(a, b, 0, false);
  p = __builtin_amdgcn_cvt_pk_fp8_f32(c, d, p, true);
  return (unsigned)p;
}
__device__ __forceinline__ f32x2 unpk_fp8_lo(unsigned u) { return __builtin_amdgcn_cvt_pk_f32_fp8(u, false); }
__device__ __forceinline__ f32x2 unpk_fp8_hi(unsigned u) { return __builtin_amdgcn_cvt_pk_f32_fp8(u, true); }
#else
#include <hip/hip_fp8.h>
__device__ __forceinline__ unsigned pack_fp8x4(float a, float b, float c, float d) {
  __hip_fp8_e4m3 qa(a), qb(b), qc(c), qd(d);
  return (unsigned)qa.__x | ((unsigned)qb.__x << 8) | ((unsigned)qc.__x << 16) | ((unsigned)qd.__x << 24);
}
__device__ __forceinline__ float unpk1(unsigned byte) {
  __hip_fp8_e4m3 t; t.__x = (__hip_fp8_storage_t)byte; return (float)t;
}
__device__ __forceinline__ f32x2 unpk_fp8_lo(unsigned u) { f32x2 r; r.x = unpk1(u & 0xff); r.y = unpk1((u >> 8) & 0xff); return r; }
__device__ __forceinline__ f32x2 unpk_fp8_hi(unsigned u) { f32x2 r; r.x = unpk1((u >> 16) & 0xff); r.y = unpk1(u >> 24); return r; }
#endif

// ---------------- merged prep: deg count + fp32 -> {bf16 XHb(=out_h), fp8 XH8} + W pack ------
// XHb/XH8 row: [ x(0-127) | h(128-255) ], rows 0..49999 only.
// Wp frag-major: idx = ((G*16 + step)*64 + q*16 + r16)*8 + e ; wrow = G*16+r16 = gate*128+o,
//   k = step*32 + q*8 + e ; k<128 Wx_self, <256 Wh_self, <384 Wx_neigh, else Wh_neigh
#define NB_DEG 3125   // 800000/256
#define NB_TOB 6250   // 50000*32/256
#define NB_PKW 1024   // 262144/256
__global__ void k_pre(const int* __restrict__ dst, int* __restrict__ deg,
                      const float* __restrict__ x, const float* __restrict__ h,
                      __bf16* __restrict__ XHb, uint8_t* __restrict__ XH8,
                      const float* __restrict__ Wx_self, const float* __restrict__ Wx_neigh,
                      const float* __restrict__ Wh_self, const float* __restrict__ Wh_neigh,
                      __bf16* __restrict__ Wp) {
  int b = blockIdx.x;
  if (b < NB_DEG) {
    int e = b * 256 + threadIdx.x;
    atomicAdd(&deg[dst[e]], 1);  // grid exact: 3125*256 == 800000
  } else if (b < NB_DEG + NB_TOB) {
    int idx = (b - NB_DEG) * 256 + threadIdx.x;  // 1.6M threads, 4 feats each, exact
    int node = idx >> 5;
    int f4 = (idx & 31) << 2;
    float4 xv = *(const float4*)(x + (size_t)node * D + f4);
    float4 hv = *(const float4*)(h + (size_t)node * D + f4);
    bf16x4 a, bb;
    a[0] = (__bf16)xv.x; a[1] = (__bf16)xv.y; a[2] = (__bf16)xv.z; a[3] = (__bf16)xv.w;
    bb[0] = (__bf16)hv.x; bb[1] = (__bf16)hv.y; bb[2] = (__bf16)hv.z; bb[3] = (__bf16)hv.w;
    __bf16* br = XHb + (size_t)node * HKD;
    *(bf16x4*)(br + f4) = a;
    *(bf16x4*)(br + 128 + f4) = bb;
    uint8_t* r8 = XH8 + (size_t)node * HKD;
    *(unsigned*)(r8 + f4) = pack_fp8x4(xv.x, xv.y, xv.z, xv.w);
    *(unsigned*)(r8 + 128 + f4) = pack_fp8x4(hv.x, hv.y, hv.z, hv.w);
  } else {
    int idx = (b - NB_DEG - NB_TOB) * 256 + threadIdx.x;  // 0..262143
    int e = idx & 7;
    int r16 = (idx >> 3) & 15;
    int q = (idx >> 7) & 3;
    int s = (idx >> 9) & 15;
    int G = idx >> 13;           // 0..31
    int wrow = G * 16 + r16;     // gate*128 + o
    int g = wrow >> 7, o = wrow & 127;
    int k = s * 32 + q * 8 + e;
    const float* src; int i;
    if (k < 128)      { src = Wx_self;  i = k; }
    else if (k < 256) { src = Wh_self;  i = k - 128; }
    else if (k < 384) { src = Wx_neigh; i = k - 256; }
    else              { src = Wh_neigh; i = k - 384; }
    Wp[idx] = (__bf16)src[(g << 14) + (i << 7) + o];
  }
}

// ---------------- single-block exclusive scan (50000 ints, 1024 thr, 8 ints/thread) ---------
__global__ __launch_bounds__(1024) void k_scan(const int* __restrict__ deg, int* __restrict__ offs,
                                               int* __restrict__ cursor, int n) {
  const int t = threadIdx.x;
  const int lane = t & 63;
  const int w = t >> 6;  // 0..15
  __shared__ int wsum[16];
  __shared__ int carry_s;
  int carry = 0;
  for (int base = 0; base < n; base += 8192) {
    int idx = base + t * 8;
    int4 v0 = make_int4(0, 0, 0, 0), v1 = make_int4(0, 0, 0, 0);
    if (idx < n) {  // n % 8 == 0, no straddle
      v0 = *(const int4*)(deg + idx);
      v1 = *(const int4*)(deg + idx + 4);
    }
    int tsum = v0.x + v0.y + v0.z + v0.w + v1.x + v1.y + v1.z + v1.w;
    int s = tsum;
#pragma unroll
    for (int d = 1; d < 64; d <<= 1) {
      int u = __shfl_up(s, d, 64);
      if (lane >= d) s += u;
    }
    if (lane == 63) wsum[w] = s;
    __syncthreads();
    int woff = 0;
    for (int i = 0; i < w; i++) woff += wsum[i];
    int excl = carry + woff + (s - tsum);
    if (idx < n) {
      int4 o0, o1;
      o0.x = excl;        o0.y = o0.x + v0.x; o0.z = o0.y + v0.y; o0.w = o0.z + v0.z;
      o1.x = o0.w + v0.w; o1.y = o1.x + v1.x; o1.z = o1.y + v1.y; o1.w = o1.z + v1.z;
      *(int4*)(offs + idx) = o0;     *(int4*)(offs + idx + 4) = o1;
      *(int4*)(cursor + idx) = o0;   *(int4*)(cursor + idx + 4) = o1;
    }
    __syncthreads();
    if (t == 0) {
      int tot = carry;
#pragma unroll
      for (int i = 0; i < 16; i++) tot += wsum[i];
      carry_s = tot;
    }
    __syncthreads();
    carry = carry_s;
  }
  if (t == 0) offs[n] = carry;
}

// ---------------- fill CSR bins ----------------
__global__ void k_fill(const int* __restrict__ src, const int* __restrict__ dst,
                       int* __restrict__ cursor, int* __restrict__ bins) {
  int e = blockIdx.x * 256 + threadIdx.x;
  if (e < N_EDGES) {
    int d = dst[e];
    int p = atomicAdd(&cursor[d], 1);
    bins[p] = src[e];
  }
}

// ---------------- gather means from fp8 rows: 1 wave/node, 8 edges in flight ----------------
// reads XH8 rows (256 B), writes ZM(=out_c) row bf16: [ mean_x(0-127) | mean_h(128-255) ]
__global__ void k_gather(const int* __restrict__ offs, const int* __restrict__ bins,
                         const uint8_t* __restrict__ XH8, __bf16* __restrict__ ZM) {
  int wid = (blockIdx.x * 256 + threadIdx.x) >> 6;
  int lane = threadIdx.x & 63;
  if (wid >= N_NODES) return;
  const int half = lane >> 5;
  const int li = lane & 31;
  const int boff = li * 8;  // byte offset into the 256B row
  int beg = offs[wid], end = offs[wid + 1];
  float a[8] = {0.f, 0.f, 0.f, 0.f, 0.f, 0.f, 0.f, 0.f};
  auto acc = [&](uint2 v) {
    f32x2 p;
    p = unpk_fp8_lo(v.x); a[0] += p.x; a[1] += p.y;
    p = unpk_fp8_hi(v.x); a[2] += p.x; a[3] += p.y;
    p = unpk_fp8_lo(v.y); a[4] += p.x; a[5] += p.y;
    p = unpk_fp8_hi(v.y); a[6] += p.x; a[7] += p.y;
  };
  int j = beg + half;
  for (; j + 6 < end; j += 8) {  // 4 edges in flight per half-wave
    int s0 = bins[j], s1 = bins[j + 2], s2 = bins[j + 4], s3 = bins[j + 6];
    uint2 v0 = *(const uint2*)(XH8 + (size_t)s0 * HKD + boff);
    uint2 v1 = *(const uint2*)(XH8 + (size_t)s1 * HKD + boff);
    uint2 v2 = *(const uint2*)(XH8 + (size_t)s2 * HKD + boff);
    uint2 v3 = *(const uint2*)(XH8 + (size_t)s3 * HKD + boff);
    acc(v0); acc(v1); acc(v2); acc(v3);
  }
  for (; j < end; j += 2) {
    uint2 v = *(const uint2*)(XH8 + (size_t)bins[j] * HKD + boff);
    acc(v);
  }
#pragma unroll
  for (int e = 0; e < 8; ++e) a[e] += __shfl_xor(a[e], 32, 64);
  int degn = end - beg;
  float inv = 1.0f / (float)(degn > 0 ? degn : 1);
  if (lane < 32) {
    bf16x8 bb;
#pragma unroll
    for (int e = 0; e < 8; ++e) bb[e] = (__bf16)(a[e] * inv);
    *(bf16x8*)(ZM + (size_t)wid * HKD + boff) = bb;
  }
}

// ---------------- fused GEMM + LSTM epilogue: barrier-free K-loop (R10 structure) -----------
// 512 thr / 8 waves, BM=64, BN=512. A-tile 64KB staged ONCE via gload_lds (linear dest,
// source chunk XOR-swizzled): chunks 0-31 self (XHb=out_h), 32-63 means (ZM=out_c); staged
// row index clamped to N_NODES-1 for pads (results discarded). One barrier; 16 K-steps of
// {Wp B-frag prefetch (ping-pong regs), ds_read A, MFMA}. No setprio (m190: hurts GEMM).
// Epilogue overwrites out_h/out_c rows owned exclusively by this block.
__global__ __launch_bounds__(512, 4) void k_gemm(
    const __bf16* __restrict__ XHb, const __bf16* __restrict__ ZM, const __bf16* __restrict__ Wp,
    const float* __restrict__ c,
    const float* __restrict__ w_ci, const float* __restrict__ w_cf, const float* __restrict__ w_co,
    const float* __restrict__ b_i, const float* __restrict__ b_f, const float* __restrict__ b_c,
    const float* __restrict__ b_o,
    float* __restrict__ out_h, float* __restrict__ out_c) {
  __shared__ __align__(16) __bf16 As[64 * KDIM];  // 64 KB; [row][64 chunks of 16B] swizzled
  const int t = threadIdx.x;
  const int lane = t & 63;
  const int w = t >> 6;  // 0..7
  const int m0 = blockIdx.x * 64;
  const int l15 = lane & 15;
  const int q = lane >> 4;  // 0..3

  // ---- stage A: 8 rounds x 512 thr x 16B; linear LDS dest, source chunk swizzled ----
#pragma unroll
  for (int i = 0; i < 8; ++i) {
    int s = i * 512 + t;
    int row = s >> 6;
    int cg = (s & 63) ^ (row & 7);
    int grow = m0 + row;
    if (grow >= N_NODES) grow = N_NODES - 1;  // pad rows: stage real data, discard later
    const __bf16* src = (cg < 32) ? (XHb + (size_t)grow * HKD + cg * 8)
                                  : (ZM + (size_t)grow * HKD + (cg - 32) * 8);
    gload_lds16(src, (__bf16*)As + (size_t)s * 8);
  }
  __syncthreads();  // ONLY barrier (drains all gload_lds)

  f32x4 acc[4][4];
#pragma unroll
  for (int m = 0; m < 4; ++m)
#pragma unroll
    for (int g = 0; g < 4; ++g) acc[m][g] = (f32x4){0.f, 0.f, 0.f, 0.f};

  // B frag base: frag g, step s -> Wp + ((g*8 + w)*16 + s)*512 + lane*8
  const __bf16* wp = Wp + (size_t)(w * 16) * 512 + lane * 8;

  bf16x8 bA[4], bB[4];
#pragma unroll
  for (int g = 0; g < 4; ++g) bA[g] = *(const bf16x8*)(wp + g * 65536);

#pragma unroll
  for (int s2 = 0; s2 < 8; ++s2) {
    {  // even step: compute bA, prefetch bB
      const int step = 2 * s2;
#pragma unroll
      for (int g = 0; g < 4; ++g)
        bB[g] = *(const bf16x8*)(wp + g * 65536 + (step + 1) * 512);
      bf16x8 af[4];
#pragma unroll
      for (int m = 0; m < 4; ++m) {
        int row = m * 16 + l15;
        int cl = (step * 4 + q) ^ (row & 7);
        af[m] = *(const bf16x8*)(As + ((size_t)row * 64 + cl) * 8);
      }
#pragma unroll
      for (int m = 0; m < 4; ++m)
#pragma unroll
        for (int g = 0; g < 4; ++g)
          acc[m][g] = __builtin_amdgcn_mfma_f32_16x16x32_bf16(af[m], bA[g], acc[m][g], 0, 0, 0);
    }
    {  // odd step: compute bB, prefetch bA
      const int step = 2 * s2 + 1;
      if (step < 15) {
#pragma unroll
        for (int g = 0; g < 4; ++g)
          bA[g] = *(const bf16x8*)(wp + g * 65536 + (step + 1) * 512);
      }
      bf16x8 af[4];
#pragma unroll
      for (int m = 0; m < 4; ++m) {
        int row = m * 16 + l15;
        int cl = (step * 4 + q) ^ (row & 7);
        af[m] = *(const bf16x8*)(As + ((size_t)row * 64 + cl) * 8);
      }
#pragma unroll
      for (int m = 0; m < 4; ++m)
#pragma unroll
        for (int g = 0; g < 4; ++g)
          acc[m][g] = __builtin_amdgcn_mfma_f32_16x16x32_bf16(af[m], bB[g], acc[m][g], 0, 0, 0);
    }
  }

  // epilogue: LSTM cell math, fused
  const int o = w * 16 + l15;
  const float wci = w_ci[o], wcf = w_cf[o], wco = w_co[o];
  const float bi = b_i[o], bfv = b_f[o], bc = b_c[o], bo = b_o[o];
#pragma unroll
  for (int m = 0; m < 4; ++m) {
#pragma unroll
    for (int r = 0; r < 4; ++r) {
      int row = m0 + m * 16 + q * 4 + r;
      if (row < N_NODES) {
        float cv = c[(size_t)row * D + o];
        float ig = sigm(acc[m][0][r] + wci * cv + bi);
        float fg = sigm(acc[m][1][r] + wcf * cv + bfv);
        float ct = tanh_fast(acc[m][2][r] + bc);
        float nc = fg * cv + ig * ct;
        float og = sigm(acc[m][3][r] + wco * nc + bo);
        out_h[(size_t)row * D + o] = og * tanh_fast(nc);
        out_c[(size_t)row * D + o] = nc;
      }
    }
  }
}

extern "C" void kernel_launch(void* const* d_in, const int* in_sizes, int n_in,
                              void* d_out, int out_size, void* d_ws, size_t ws_size,
                              hipStream_t stream) {
  const float* x = (const float*)d_in[0];
  const float* h = (const float*)d_in[1];
  const float* c = (const float*)d_in[2];
  const float* Wx_self = (const float*)d_in[3];
  const float* Wx_neigh = (const float*)d_in[4];
  const float* Wh_self = (const float*)d_in[5];
  const float* Wh_neigh = (const float*)d_in[6];
  const float* w_ci = (const float*)d_in[7];
  const float* w_cf = (const float*)d_in[8];
  const float* w_co = (const float*)d_in[9];
  const float* b_i = (const float*)d_in[10];
  const float* b_f = (const float*)d_in[11];
  const float* b_c = (const float*)d_in[12];
  const float* b_o = (const float*)d_in[13];
  const int* src = (const int*)d_in[14];
  const int* dst = (const int*)d_in[15];

  char* ws = (char*)d_ws;
  int* deg = (int*)(ws);                       // 50000 ints
  int* offs = (int*)(ws + 200704);             // 50001 ints
  int* cursor = (int*)(ws + 400896);           // 50000 ints
  int* bins = (int*)(ws + 601088);             // 800000 ints (ends 3,801,088)
  uint8_t* XH8 = (uint8_t*)(ws + 4194304);     // [50000][256] fp8 = 12.8 MB
  __bf16* Wp = (__bf16*)(ws + 17039360);       // [262144] bf16 frag-major

  float* out_h = (float*)d_out;
  float* out_c = out_h + (size_t)N_NODES * D;
  // staging aliases inside d_out (block-local rows; overwritten by epilogue after reads)
  __bf16* XHb = (__bf16*)out_h;  // [50000][256] bf16 self rows
  __bf16* ZM = (__bf16*)out_c;   // [50000][256] bf16 mean rows

  hipMemsetAsync(deg, 0, N_NODES * sizeof(int), stream);
  k_pre<<<NB_DEG + NB_TOB + NB_PKW, 256, 0, stream>>>(dst, deg, x, h, XHb, XH8,
                                                      Wx_self, Wx_neigh, Wh_self, Wh_neigh, Wp);
  k_scan<<<1, 1024, 0, stream>>>(deg, offs, cursor, N_NODES);
  k_fill<<<(N_EDGES + 255) / 256, 256, 0, stream>>>(src, dst, cursor, bins);
  k_gather<<<(N_NODES + 3) / 4, 256, 0, stream>>>(offs, bins, XH8, ZM);
  k_gemm<<<NPAD / 64, 512, 0, stream>>>(XHb, ZM, Wp, c, w_ci, w_cf, w_co,
                                        b_i, b_f, b_c, b_o, out_h, out_c);
}

// Round 18
// 201.128 us; speedup vs baseline: 3.3130x; 1.0199x over previous
//
#include <hip/hip_runtime.h>
#include <hip/hip_bf16.h>
#include <stdint.h>

#define N_NODES 50000
#define N_EDGES 800000
#define D 128
#define NPAD 50048
#define HKD 256   // bf16/fp8 row col count
#define KDIM 512

typedef __attribute__((ext_vector_type(8))) __bf16 bf16x8;
typedef __attribute__((ext_vector_type(4))) __bf16 bf16x4;
typedef __attribute__((ext_vector_type(4))) float f32x4;
typedef __attribute__((ext_vector_type(2))) float f32x2;

__device__ __forceinline__ void gload_lds16(const void* g, void* l) {
  __builtin_amdgcn_global_load_lds(
      (const __attribute__((address_space(1))) unsigned int*)(uintptr_t)g,
      (__attribute__((address_space(3))) unsigned int*)(uint32_t)(uintptr_t)l,
      16, 0, 0);
}

__device__ __forceinline__ float sigm(float v) { return 1.0f / (1.0f + __expf(-v)); }
__device__ __forceinline__ float tanh_fast(float v) { return 1.0f - 2.0f / (1.0f + __expf(2.0f * v)); }

// ---- fp8 e4m3 (OCP) pack/unpack via gfx950 HW converts (fallback: hip_fp8 API) ----
#if defined(__has_builtin) && __has_builtin(__builtin_amdgcn_cvt_pk_fp8_f32) && __has_builtin(__builtin_amdgcn_cvt_pk_f32_fp8)
__device__ __forceinline__ unsigned pack_fp8x4(float a, float b, float c, float d) {
  int p = __builtin_amdgcn_cvt_pk_fp8_f32(a, b, 0, false);
  p = __builtin_amdgcn_cvt_pk_fp8_f32(c, d, p, true);
  return (unsigned)p;
}
__device__ __forceinline__ f32x2 unpk_fp8_lo(unsigned u) { return __builtin_amdgcn_cvt_pk_f32_fp8(u, false); }
__device__ __forceinline__ f32x2 unpk_fp8_hi(unsigned u) { return __builtin_amdgcn_cvt_pk_f32_fp8(u, true); }
#else
#include <hip/hip_fp8.h>
__device__ __forceinline__ unsigned pack_fp8x4(float a, float b, float c, float d) {
  __hip_fp8_e4m3 qa(a), qb(b), qc(c), qd(d);
  return (unsigned)qa.__x | ((unsigned)qb.__x << 8) | ((unsigned)qc.__x << 16) | ((unsigned)qd.__x << 24);
}
__device__ __forceinline__ float unpk1(unsigned byte) {
  __hip_fp8_e4m3 t; t.__x = (__hip_fp8_storage_t)byte; return (float)t;
}
__device__ __forceinline__ f32x2 unpk_fp8_lo(unsigned u) { f32x2 r; r.x = unpk1(u & 0xff); r.y = unpk1((u >> 8) & 0xff); return r; }
__device__ __forceinline__ f32x2 unpk_fp8_hi(unsigned u) { f32x2 r; r.x = unpk1((u >> 16) & 0xff); r.y = unpk1(u >> 24); return r; }
#endif

// ---------------- merged prep: deg count + fp32 -> {bf16 XHb(=out_h), fp8 XH8} + W pack ------
// XHb/XH8 row: [ x(0-127) | h(128-255) ], rows 0..49999 only.
// Wp frag-major: idx = ((G*16 + step)*64 + q*16 + r16)*8 + e ; wrow = G*16+r16 = gate*128+o,
//   k = step*32 + q*8 + e ; k<128 Wx_self, <256 Wh_self, <384 Wx_neigh, else Wh_neigh
#define NB_DEG 3125   // 800000/256
#define NB_TOB 6250   // 50000*32/256
#define NB_PKW 1024   // 262144/256
__global__ void k_pre(const int* __restrict__ dst, int* __restrict__ deg,
                      const float* __restrict__ x, const float* __restrict__ h,
                      __bf16* __restrict__ XHb, uint8_t* __restrict__ XH8,
                      const float* __restrict__ Wx_self, const float* __restrict__ Wx_neigh,
                      const float* __restrict__ Wh_self, const float* __restrict__ Wh_neigh,
                      __bf16* __restrict__ Wp) {
  int b = blockIdx.x;
  if (b < NB_DEG) {
    int e = b * 256 + threadIdx.x;
    atomicAdd(&deg[dst[e]], 1);  // grid exact: 3125*256 == 800000
  } else if (b < NB_DEG + NB_TOB) {
    int idx = (b - NB_DEG) * 256 + threadIdx.x;  // 1.6M threads, 4 feats each, exact
    int node = idx >> 5;
    int f4 = (idx & 31) << 2;
    float4 xv = *(const float4*)(x + (size_t)node * D + f4);
    float4 hv = *(const float4*)(h + (size_t)node * D + f4);
    bf16x4 a, bb;
    a[0] = (__bf16)xv.x; a[1] = (__bf16)xv.y; a[2] = (__bf16)xv.z; a[3] = (__bf16)xv.w;
    bb[0] = (__bf16)hv.x; bb[1] = (__bf16)hv.y; bb[2] = (__bf16)hv.z; bb[3] = (__bf16)hv.w;
    __bf16* br = XHb + (size_t)node * HKD;
    *(bf16x4*)(br + f4) = a;
    *(bf16x4*)(br + 128 + f4) = bb;
    uint8_t* r8 = XH8 + (size_t)node * HKD;
    *(unsigned*)(r8 + f4) = pack_fp8x4(xv.x, xv.y, xv.z, xv.w);
    *(unsigned*)(r8 + 128 + f4) = pack_fp8x4(hv.x, hv.y, hv.z, hv.w);
  } else {
    int idx = (b - NB_DEG - NB_TOB) * 256 + threadIdx.x;  // 0..262143
    int e = idx & 7;
    int r16 = (idx >> 3) & 15;
    int q = (idx >> 7) & 3;
    int s = (idx >> 9) & 15;
    int G = idx >> 13;           // 0..31
    int wrow = G * 16 + r16;     // gate*128 + o
    int g = wrow >> 7, o = wrow & 127;
    int k = s * 32 + q * 8 + e;
    const float* src; int i;
    if (k < 128)      { src = Wx_self;  i = k; }
    else if (k < 256) { src = Wh_self;  i = k - 128; }
    else if (k < 384) { src = Wx_neigh; i = k - 256; }
    else              { src = Wh_neigh; i = k - 384; }
    Wp[idx] = (__bf16)src[(g << 14) + (i << 7) + o];
  }
}

// ---------------- single-block exclusive scan (50000 ints, 1024 thr, 8 ints/thread) ---------
__global__ __launch_bounds__(1024) void k_scan(const int* __restrict__ deg, int* __restrict__ offs,
                                               int* __restrict__ cursor, int n) {
  const int t = threadIdx.x;
  const int lane = t & 63;
  const int w = t >> 6;  // 0..15
  __shared__ int wsum[16];
  __shared__ int carry_s;
  int carry = 0;
  for (int base = 0; base < n; base += 8192) {
    int idx = base + t * 8;
    int4 v0 = make_int4(0, 0, 0, 0), v1 = make_int4(0, 0, 0, 0);
    if (idx < n) {  // n % 8 == 0, no straddle
      v0 = *(const int4*)(deg + idx);
      v1 = *(const int4*)(deg + idx + 4);
    }
    int tsum = v0.x + v0.y + v0.z + v0.w + v1.x + v1.y + v1.z + v1.w;
    int s = tsum;
#pragma unroll
    for (int d = 1; d < 64; d <<= 1) {
      int u = __shfl_up(s, d, 64);
      if (lane >= d) s += u;
    }
    if (lane == 63) wsum[w] = s;
    __syncthreads();
    int woff = 0;
    for (int i = 0; i < w; i++) woff += wsum[i];
    int excl = carry + woff + (s - tsum);
    if (idx < n) {
      int4 o0, o1;
      o0.x = excl;        o0.y = o0.x + v0.x; o0.z = o0.y + v0.y; o0.w = o0.z + v0.z;
      o1.x = o0.w + v0.w; o1.y = o1.x + v1.x; o1.z = o1.y + v1.y; o1.w = o1.z + v1.z;
      *(int4*)(offs + idx) = o0;     *(int4*)(offs + idx + 4) = o1;
      *(int4*)(cursor + idx) = o0;   *(int4*)(cursor + idx + 4) = o1;
    }
    __syncthreads();
    if (t == 0) {
      int tot = carry;
#pragma unroll
      for (int i = 0; i < 16; i++) tot += wsum[i];
      carry_s = tot;
    }
    __syncthreads();
    carry = carry_s;
  }
  if (t == 0) offs[n] = carry;
}

// ---------------- fill CSR bins ----------------
__global__ void k_fill(const int* __restrict__ src, const int* __restrict__ dst,
                       int* __restrict__ cursor, int* __restrict__ bins) {
  int e = blockIdx.x * 256 + threadIdx.x;
  if (e < N_EDGES) {
    int d = dst[e];
    int p = atomicAdd(&cursor[d], 1);
    bins[p] = src[e];
  }
}

// ---------------- gather means: 1 wave/node, 16B/lane, 4 edges concurrent (quarter-waves) ----
// reads XH8 rows (256 B, 16 lanes x uint4), writes ZM(=out_c) bf16 row. Half the memory
// requests of the 8B/lane version at identical bytes (request-rate-bound hypothesis).
__global__ void k_gather(const int* __restrict__ offs, const int* __restrict__ bins,
                         const uint8_t* __restrict__ XH8, __bf16* __restrict__ ZM) {
  int wid = (blockIdx.x * 256 + threadIdx.x) >> 6;
  int lane = threadIdx.x & 63;
  if (wid >= N_NODES) return;
  const int qw = lane >> 4;   // 0..3: quarter-wave, one edge each
  const int li = lane & 15;   // 16 lanes per edge-row
  const int boff = li * 16;   // 16 B per lane
  int beg = offs[wid], end = offs[wid + 1];
  float a[16], a2[16];
#pragma unroll
  for (int e = 0; e < 16; ++e) { a[e] = 0.f; a2[e] = 0.f; }
  auto acc16 = [&](uint4 v, float* aa) {
    f32x2 p;
    p = unpk_fp8_lo(v.x); aa[0] += p.x;  aa[1] += p.y;
    p = unpk_fp8_hi(v.x); aa[2] += p.x;  aa[3] += p.y;
    p = unpk_fp8_lo(v.y); aa[4] += p.x;  aa[5] += p.y;
    p = unpk_fp8_hi(v.y); aa[6] += p.x;  aa[7] += p.y;
    p = unpk_fp8_lo(v.z); aa[8] += p.x;  aa[9] += p.y;
    p = unpk_fp8_hi(v.z); aa[10] += p.x; aa[11] += p.y;
    p = unpk_fp8_lo(v.w); aa[12] += p.x; aa[13] += p.y;
    p = unpk_fp8_hi(v.w); aa[14] += p.x; aa[15] += p.y;
  };
  int j = beg + qw;
  for (; j + 4 < end; j += 8) {  // 2 edges in flight per quarter-wave (8/wave)
    uint4 v0 = *(const uint4*)(XH8 + (size_t)bins[j] * HKD + boff);
    uint4 v1 = *(const uint4*)(XH8 + (size_t)bins[j + 4] * HKD + boff);
    acc16(v0, a); acc16(v1, a2);
  }
  if (j < end) {
    uint4 v0 = *(const uint4*)(XH8 + (size_t)bins[j] * HKD + boff);
    acc16(v0, a);
  }
#pragma unroll
  for (int e = 0; e < 16; ++e) {
    a[e] += a2[e];
    a[e] += __shfl_xor(a[e], 16, 64);
    a[e] += __shfl_xor(a[e], 32, 64);
  }
  int degn = end - beg;
  float inv = 1.0f / (float)(degn > 0 ? degn : 1);
  if (lane < 16) {
    bf16x8 b0, b1;
#pragma unroll
    for (int e = 0; e < 8; ++e) {
      b0[e] = (__bf16)(a[e] * inv);
      b1[e] = (__bf16)(a[8 + e] * inv);
    }
    __bf16* zr = ZM + (size_t)wid * HKD + li * 16;
    *(bf16x8*)zr = b0;
    *(bf16x8*)(zr + 8) = b1;
  }
}

// ---------------- fused GEMM + LSTM epilogue: barrier-free K-loop (R10 structure) -----------
// 512 thr / 8 waves, BM=64, BN=512. A-tile 64KB staged ONCE via gload_lds (linear dest,
// source chunk XOR-swizzled): chunks 0-31 self (XHb=out_h), 32-63 means (ZM=out_c); staged
// row index clamped to N_NODES-1 for pads (results discarded). One barrier; 16 K-steps of
// {Wp B-frag prefetch (ping-pong regs), ds_read A, MFMA}. No setprio (m190: hurts GEMM).
// Epilogue overwrites out_h/out_c rows owned exclusively by this block.
__global__ __launch_bounds__(512, 4) void k_gemm(
    const __bf16* __restrict__ XHb, const __bf16* __restrict__ ZM, const __bf16* __restrict__ Wp,
    const float* __restrict__ c,
    const float* __restrict__ w_ci, const float* __restrict__ w_cf, const float* __restrict__ w_co,
    const float* __restrict__ b_i, const float* __restrict__ b_f, const float* __restrict__ b_c,
    const float* __restrict__ b_o,
    float* __restrict__ out_h, float* __restrict__ out_c) {
  __shared__ __align__(16) __bf16 As[64 * KDIM];  // 64 KB; [row][64 chunks of 16B] swizzled
  const int t = threadIdx.x;
  const int lane = t & 63;
  const int w = t >> 6;  // 0..7
  const int m0 = blockIdx.x * 64;
  const int l15 = lane & 15;
  const int q = lane >> 4;  // 0..3

  // ---- stage A: 8 rounds x 512 thr x 16B; linear LDS dest, source chunk swizzled ----
#pragma unroll
  for (int i = 0; i < 8; ++i) {
    int s = i * 512 + t;
    int row = s >> 6;
    int cg = (s & 63) ^ (row & 7);
    int grow = m0 + row;
    if (grow >= N_NODES) grow = N_NODES - 1;  // pad rows: stage real data, discard later
    const __bf16* src = (cg < 32) ? (XHb + (size_t)grow * HKD + cg * 8)
                                  : (ZM + (size_t)grow * HKD + (cg - 32) * 8);
    gload_lds16(src, (__bf16*)As + (size_t)s * 8);
  }
  __syncthreads();  // ONLY barrier (drains all gload_lds)

  f32x4 acc[4][4];
#pragma unroll
  for (int m = 0; m < 4; ++m)
#pragma unroll
    for (int g = 0; g < 4; ++g) acc[m][g] = (f32x4){0.f, 0.f, 0.f, 0.f};

  // B frag base: frag g, step s -> Wp + ((g*8 + w)*16 + s)*512 + lane*8
  const __bf16* wp = Wp + (size_t)(w * 16) * 512 + lane * 8;

  bf16x8 bA[4], bB[4];
#pragma unroll
  for (int g = 0; g < 4; ++g) bA[g] = *(const bf16x8*)(wp + g * 65536);

#pragma unroll
  for (int s2 = 0; s2 < 8; ++s2) {
    {  // even step: compute bA, prefetch bB
      const int step = 2 * s2;
#pragma unroll
      for (int g = 0; g < 4; ++g)
        bB[g] = *(const bf16x8*)(wp + g * 65536 + (step + 1) * 512);
      bf16x8 af[4];
#pragma unroll
      for (int m = 0; m < 4; ++m) {
        int row = m * 16 + l15;
        int cl = (step * 4 + q) ^ (row & 7);
        af[m] = *(const bf16x8*)(As + ((size_t)row * 64 + cl) * 8);
      }
#pragma unroll
      for (int m = 0; m < 4; ++m)
#pragma unroll
        for (int g = 0; g < 4; ++g)
          acc[m][g] = __builtin_amdgcn_mfma_f32_16x16x32_bf16(af[m], bA[g], acc[m][g], 0, 0, 0);
    }
    {  // odd step: compute bB, prefetch bA
      const int step = 2 * s2 + 1;
      if (step < 15) {
#pragma unroll
        for (int g = 0; g < 4; ++g)
          bA[g] = *(const bf16x8*)(wp + g * 65536 + (step + 1) * 512);
      }
      bf16x8 af[4];
#pragma unroll
      for (int m = 0; m < 4; ++m) {
        int row = m * 16 + l15;
        int cl = (step * 4 + q) ^ (row & 7);
        af[m] = *(const bf16x8*)(As + ((size_t)row * 64 + cl) * 8);
      }
#pragma unroll
      for (int m = 0; m < 4; ++m)
#pragma unroll
        for (int g = 0; g < 4; ++g)
          acc[m][g] = __builtin_amdgcn_mfma_f32_16x16x32_bf16(af[m], bB[g], acc[m][g], 0, 0, 0);
    }
  }

  // epilogue: LSTM cell math, fused
  const int o = w * 16 + l15;
  const float wci = w_ci[o], wcf = w_cf[o], wco = w_co[o];
  const float bi = b_i[o], bfv = b_f[o], bc = b_c[o], bo = b_o[o];
#pragma unroll
  for (int m = 0; m < 4; ++m) {
#pragma unroll
    for (int r = 0; r < 4; ++r) {
      int row = m0 + m * 16 + q * 4 + r;
      if (row < N_NODES) {
        float cv = c[(size_t)row * D + o];
        float ig = sigm(acc[m][0][r] + wci * cv + bi);
        float fg = sigm(acc[m][1][r] + wcf * cv + bfv);
        float ct = tanh_fast(acc[m][2][r] + bc);
        float nc = fg * cv + ig * ct;
        float og = sigm(acc[m][3][r] + wco * nc + bo);
        out_h[(size_t)row * D + o] = og * tanh_fast(nc);
        out_c[(size_t)row * D + o] = nc;
      }
    }
  }
}

extern "C" void kernel_launch(void* const* d_in, const int* in_sizes, int n_in,
                              void* d_out, int out_size, void* d_ws, size_t ws_size,
                              hipStream_t stream) {
  const float* x = (const float*)d_in[0];
  const float* h = (const float*)d_in[1];
  const float* c = (const float*)d_in[2];
  const float* Wx_self = (const float*)d_in[3];
  const float* Wx_neigh = (const float*)d_in[4];
  const float* Wh_self = (const float*)d_in[5];
  const float* Wh_neigh = (const float*)d_in[6];
  const float* w_ci = (const float*)d_in[7];
  const float* w_cf = (const float*)d_in[8];
  const float* w_co = (const float*)d_in[9];
  const float* b_i = (const float*)d_in[10];
  const float* b_f = (const float*)d_in[11];
  const float* b_c = (const float*)d_in[12];
  const float* b_o = (const float*)d_in[13];
  const int* src = (const int*)d_in[14];
  const int* dst = (const int*)d_in[15];

  char* ws = (char*)d_ws;
  int* deg = (int*)(ws);                       // 50000 ints
  int* offs = (int*)(ws + 200704);             // 50001 ints
  int* cursor = (int*)(ws + 400896);           // 50000 ints
  int* bins = (int*)(ws + 601088);             // 800000 ints (ends 3,801,088)
  uint8_t* XH8 = (uint8_t*)(ws + 4194304);     // [50000][256] fp8 = 12.8 MB
  __bf16* Wp = (__bf16*)(ws + 17039360);       // [262144] bf16 frag-major

  float* out_h = (float*)d_out;
  float* out_c = out_h + (size_t)N_NODES * D;
  // staging aliases inside d_out (block-local rows; overwritten by epilogue after reads)
  __bf16* XHb = (__bf16*)out_h;  // [50000][256] bf16 self rows
  __bf16* ZM = (__bf16*)out_c;   // [50000][256] bf16 mean rows

  hipMemsetAsync(deg, 0, N_NODES * sizeof(int), stream);
  k_pre<<<NB_DEG + NB_TOB + NB_PKW, 256, 0, stream>>>(dst, deg, x, h, XHb, XH8,
                                                      Wx_self, Wx_neigh, Wh_self, Wh_neigh, Wp);
  k_scan<<<1, 1024, 0, stream>>>(deg, offs, cursor, N_NODES);
  k_fill<<<(N_EDGES + 255) / 256, 256, 0, stream>>>(src, dst, cursor, bins);
  k_gather<<<(N_NODES + 3) / 4, 256, 0, stream>>>(offs, bins, XH8, ZM);
  k_gemm<<<NPAD / 64, 512, 0, stream>>>(XHb, ZM, Wp, c, w_ci, w_cf, w_co,
                                        b_i, b_f, b_c, b_o, out_h, out_c);
}